// Round 5
// baseline (61.346 us; speedup 1.0000x reference)
//
#include <hip/hip_runtime.h>
#include <hip/hip_bf16.h>
#include <hip/hip_cooperative_groups.h>

namespace cg = cooperative_groups;

#define RES_    2048
#define CSTEPS  128     // steps per workgroup
#define NWG     512     // 65536 / CSTEPS
#define TILE_   48      // span <= 8px movement + 32 window = 40 <= 48 (3x3 MFMA tiles)
#define KPAD    136     // 128 + 8 halfs pad: row stride 272B, 16B-aligned
#define NTHR    576     // 9 waves: one 16x16 output tile each
#define ZCHUNK  2048    // float4s per WG: 2048*2048 floats / 512 WGs / 4

typedef _Float16 half8 __attribute__((ext_vector_type(8)));
typedef float   float4_ __attribute__((ext_vector_type(4)));

__global__ __launch_bounds__(NTHR) void bezier_fused(const float* __restrict__ cp,
                                                     float* __restrict__ out) {
    __shared__ _Float16 sExT[TILE_][KPAD];   // [col_offset][step], masked exp_x
    __shared__ _Float16 sEyT[TILE_][KPAD];   // [col_offset][step], masked exp_y
    __shared__ float s_cx[CSTEPS], s_cy[CSTEPS];
    __shared__ int   s_bx[CSTEPS], s_by[CSTEPS];
    __shared__ int   s_Ax, s_Ay;

    const int tid = threadIdx.x;

    // ---- Zero my 1/512 slice of the raster (global-only; overlaps phases A-C) ----
    {
        float4_* oz = (float4_*)out + (size_t)blockIdx.x * ZCHUNK;
        #pragma unroll
        for (int i = tid; i < ZCHUNK; i += NTHR)
            oz[i] = float4_{0.f, 0.f, 0.f, 0.f};
    }

    // ---- Phase A: per-step curve position & block corner (exact ref float32 math) ----
    if (tid < CSTEPS) {
        const int gs = blockIdx.x * CSTEPS + tid;
        const float tl = (float)((double)gs / 65535.0);      // linspace(0,1,STEPS)
        const float to = (float)gs * (1.0f / 65536.0f);      // arange(STEPS)/STEPS (exact)
        const float p0x = cp[0], p0y = cp[1], p1x = cp[2], p1y = cp[3], p2x = cp[4], p2y = cp[5];
        const float ax = __fadd_rn(p0x, __fmul_rn(__fsub_rn(p1x, p0x), tl));
        const float ay = __fadd_rn(p0y, __fmul_rn(__fsub_rn(p1y, p0y), tl));
        const float bxf = __fadd_rn(p1x, __fmul_rn(__fsub_rn(p2x, p1x), tl));
        const float byf = __fadd_rn(p1y, __fmul_rn(__fsub_rn(p2y, p1y), tl));
        const float cx = __fadd_rn(ax, __fmul_rn(to, __fsub_rn(bxf, ax)));
        const float cy = __fadd_rn(ay, __fmul_rn(to, __fsub_rn(byf, ay)));
        const int bxi = min(max((int)floorf(__fmul_rn(2048.0f, cx)) - 16, 0), RES_ - 32);
        const int byi = min(max((int)floorf(__fmul_rn(2048.0f, cy)) - 16, 0), RES_ - 32);
        s_cx[tid] = cx; s_cy[tid] = cy; s_bx[tid] = bxi; s_by[tid] = byi;
        if (tid == 0) {
            // |bx_s - bx_0| <= 8 over 128 steps -> windows subset of [bx0-8, bx0+40) (48 wide)
            s_Ax = min(max(bxi - 8, 0), RES_ - TILE_);
            s_Ay = min(max(byi - 8, 0), RES_ - TILE_);
        }
    }
    __syncthreads();
    const int Ax = s_Ax, Ay = s_Ay;

    // ---- Phase B: fill masked transposed f16 exp tables ----
    // 2 tables * 48 cols * 16 step-groups(8) = 1536 items over 576 threads
    for (int it = tid; it < 2 * TILE_ * (CSTEPS / 8); it += NTHR) {
        const int half_ = TILE_ * (CSTEPS / 8);       // 768
        const int table = (it >= half_);
        const int rem   = it - table * half_;
        const int o     = rem >> 4;                   // tile col offset 0..47
        const int s0    = (rem & 15) * 8;             // step group start
        const float* cc = table ? s_cy : s_cx;
        const int*   bb = table ? s_by : s_bx;
        const int  base = table ? Ay : Ax;
        const float ci  = (float)(base + o) * (1.0f / 2048.0f);   // exact (pow2 div)
        half8 v;
        #pragma unroll
        for (int j = 0; j < 8; ++j) {
            const int s = s0 + j;
            const float d = __fsub_rn(cc[s], ci);
            const float e = __expf(-__fmul_rn(__fmul_rn(d, d), 5000.0f));
            const unsigned orel = (unsigned)(base + o - bb[s]);
            v[j] = (orel < 32u) ? (_Float16)e : (_Float16)0.0f;
        }
        *(half8*)(table ? &sEyT[o][s0] : &sExT[o][s0]) = v;
    }
    __syncthreads();

    // ---- Phase C: 48x48 tile = Ex^T (48x128) * Ey (128x48); 9 waves, 1 tile each ----
    const int lane = tid & 63;
    const int wid  = tid >> 6;          // 0..8
    const int mt   = wid / 3, nt = wid - mt * 3;
    const int arow = mt * 16 + (lane & 15);
    const int bcol = nt * 16 + (lane & 15);
    const int kgrp = (lane >> 4) * 8;
    float4_ acc = {0.f, 0.f, 0.f, 0.f};
    #pragma unroll
    for (int kb = 0; kb < CSTEPS / 32; ++kb) {
        const half8 aF = *(const half8*)&sExT[arow][kb * 32 + kgrp];
        const half8 bF = *(const half8*)&sEyT[bcol][kb * 32 + kgrp];
        acc = __builtin_amdgcn_mfma_f32_16x16x32_f16(aF, bF, acc, 0, 0, 0);
    }

    // ---- Grid barrier: all zero-writes visible before any atomic flush ----
    cg::this_grid().sync();

    // ---- Flush: C/D layout col = lane&15, row = (lane>>4)*4 + reg (confirmed R1) ----
    const int coll = lane & 15;
    const int rowb = (lane >> 4) * 4;
    #pragma unroll
    for (int r = 0; r < 4; ++r) {
        const float v = acc[r];
        if (v != 0.0f) {   // nonzero only inside valid clamped windows
            const int gx = Ax + mt * 16 + rowb + r;
            const int gy = Ay + nt * 16 + coll;
            atomicAdd(&out[gx * RES_ + gy], v * (1.0f / 65536.0f));  // /STEPS exact (pow2)
        }
    }
}

extern "C" void kernel_launch(void* const* d_in, const int* in_sizes, int n_in,
                              void* d_out, int out_size, void* d_ws, size_t ws_size,
                              hipStream_t stream) {
    const float* cp = (const float*)d_in[0];
    float* out = (float*)d_out;
    void* args[] = { (void*)&cp, (void*)&out };
    // Single cooperative kernel: zero (overlapped with exp/MFMA build) -> grid sync -> flush
    hipLaunchCooperativeKernel((const void*)bezier_fused, dim3(NWG), dim3(NTHR),
                               args, 0, stream);
}

// Round 6
// 36.926 us; speedup vs baseline: 1.6613x; 1.6613x over previous
//
#include <hip/hip_runtime.h>
#include <hip/hip_bf16.h>

#define RES_    2048
#define CSTEPS  128     // steps per chunk
#define NCH     512     // 65536 / CSTEPS
#define TILE_   48      // chunk tile: span <= 8px + 32 window = 40 <= 48
#define KPAD    136     // 128 + 8 halfs pad: row stride 272B, 16B-aligned
#define NTHR1   576     // 9 waves: one 16x16 subtile each
#define WSTILE  2304    // 48*48 floats per chunk tile
#define NTHR2   256     // gather kernel: 4 waves

typedef _Float16 half8  __attribute__((ext_vector_type(8)));
typedef float   float4_ __attribute__((ext_vector_type(4)));

// ---------------- Kernel 1: per-chunk 48x48 tile -> workspace (no atomics) ----------------
__global__ __launch_bounds__(NTHR1) void bezier_chunks(const float* __restrict__ cp,
                                                       float* __restrict__ wst,
                                                       int* __restrict__ wsa) {
    __shared__ _Float16 sExT[TILE_][KPAD];
    __shared__ _Float16 sEyT[TILE_][KPAD];
    __shared__ float s_cx[CSTEPS], s_cy[CSTEPS];
    __shared__ int   s_bx[CSTEPS], s_by[CSTEPS];
    __shared__ int   s_Ax, s_Ay;

    const int tid = threadIdx.x;

    // ---- Phase A: exact ref float32 step math (proven R1-R4) ----
    if (tid < CSTEPS) {
        const int gs = blockIdx.x * CSTEPS + tid;
        const float tl = (float)((double)gs / 65535.0);      // linspace(0,1,STEPS)
        const float to = (float)gs * (1.0f / 65536.0f);      // arange(STEPS)/STEPS (exact)
        const float p0x = cp[0], p0y = cp[1], p1x = cp[2], p1y = cp[3], p2x = cp[4], p2y = cp[5];
        const float ax = __fadd_rn(p0x, __fmul_rn(__fsub_rn(p1x, p0x), tl));
        const float ay = __fadd_rn(p0y, __fmul_rn(__fsub_rn(p1y, p0y), tl));
        const float bxf = __fadd_rn(p1x, __fmul_rn(__fsub_rn(p2x, p1x), tl));
        const float byf = __fadd_rn(p1y, __fmul_rn(__fsub_rn(p2y, p1y), tl));
        const float cx = __fadd_rn(ax, __fmul_rn(to, __fsub_rn(bxf, ax)));
        const float cy = __fadd_rn(ay, __fmul_rn(to, __fsub_rn(byf, ay)));
        const int bxi = min(max((int)floorf(__fmul_rn(2048.0f, cx)) - 16, 0), RES_ - 32);
        const int byi = min(max((int)floorf(__fmul_rn(2048.0f, cy)) - 16, 0), RES_ - 32);
        s_cx[tid] = cx; s_cy[tid] = cy; s_bx[tid] = bxi; s_by[tid] = byi;
        if (tid == 0) {
            // |bx_s - bx_0| <= 8 over 128 steps -> all windows inside [bx0-8, bx0+40)
            s_Ax = min(max(bxi - 8, 0), RES_ - TILE_);
            s_Ay = min(max(byi - 8, 0), RES_ - TILE_);
            wsa[2 * blockIdx.x]     = s_Ax;
            wsa[2 * blockIdx.x + 1] = s_Ay;
        }
    }
    __syncthreads();
    const int Ax = s_Ax, Ay = s_Ay;

    // ---- Phase B: masked transposed f16 exp tables ----
    for (int it = tid; it < 2 * TILE_ * (CSTEPS / 8); it += NTHR1) {
        const int half_ = TILE_ * (CSTEPS / 8);       // 768
        const int table = (it >= half_);
        const int rem   = it - table * half_;
        const int o     = rem >> 4;
        const int s0    = (rem & 15) * 8;
        const float* cc = table ? s_cy : s_cx;
        const int*   bb = table ? s_by : s_bx;
        const int  base = table ? Ay : Ax;
        const float ci  = (float)(base + o) * (1.0f / 2048.0f);
        half8 v;
        #pragma unroll
        for (int j = 0; j < 8; ++j) {
            const int s = s0 + j;
            const float d = __fsub_rn(cc[s], ci);
            const float e = __expf(-__fmul_rn(__fmul_rn(d, d), 5000.0f));
            const unsigned orel = (unsigned)(base + o - bb[s]);
            v[j] = (orel < 32u) ? (_Float16)e : (_Float16)0.0f;
        }
        *(half8*)(table ? &sEyT[o][s0] : &sExT[o][s0]) = v;
    }
    __syncthreads();

    // ---- Phase C: 48x48 = Ex^T (48x128) * Ey (128x48); 9 waves, one 16x16 each ----
    const int lane = tid & 63;
    const int wid  = tid >> 6;
    const int mt   = wid / 3, nt = wid - mt * 3;
    const int arow = mt * 16 + (lane & 15);
    const int bcol = nt * 16 + (lane & 15);
    const int kgrp = (lane >> 4) * 8;
    float4_ acc = {0.f, 0.f, 0.f, 0.f};
    #pragma unroll
    for (int kb = 0; kb < CSTEPS / 32; ++kb) {
        const half8 aF = *(const half8*)&sExT[arow][kb * 32 + kgrp];
        const half8 bF = *(const half8*)&sEyT[bcol][kb * 32 + kgrp];
        acc = __builtin_amdgcn_mfma_f32_16x16x32_f16(aF, bF, acc, 0, 0, 0);
    }

    // ---- Flush: plain stores of the full 48x48 tile (poisoned ws: write every cell) ----
    float* wt = wst + (size_t)blockIdx.x * WSTILE;
    const int coll = lane & 15;
    const int rowb = (lane >> 4) * 4;
    #pragma unroll
    for (int r = 0; r < 4; ++r)
        wt[(mt * 16 + rowb + r) * TILE_ + nt * 16 + coll] = acc[r] * (1.0f / 65536.0f);
}

// ---------------- Kernel 2: gather 32x32 output tile, non-atomic, full coverage ----------------
__global__ __launch_bounds__(NTHR2) void bezier_gather(const float* __restrict__ wst,
                                                       const int* __restrict__ wsa,
                                                       float* __restrict__ out) {
    __shared__ unsigned short s_c[NCH];
    __shared__ short s_ax[NCH], s_ay[NCH];
    __shared__ int s_wcnt[8];
    __shared__ int s_cnt;

    const int tid = threadIdx.x;
    const int bid = blockIdx.x;
    const int Tx = (bid >> 6) * 32;
    const int Ty = (bid & 63) * 32;
    const int lane = tid & 63;
    const int w = tid >> 6;                    // 0..3
    const unsigned long long below = (lane == 63) ? ~0ull >> 1 : (1ull << lane) - 1ull;

    // exact anchor-bbox overlap test: 2 rounds x 256 chunks
    bool ovr[2]; unsigned long long mr[2]; int axr[2], ayr[2];
    #pragma unroll
    for (int r = 0; r < 2; ++r) {
        const int c = r * 256 + tid;
        axr[r] = wsa[2 * c]; ayr[r] = wsa[2 * c + 1];
        ovr[r] = (axr[r] <= Tx + 31) && (axr[r] + TILE_ - 1 >= Tx) &&
                 (ayr[r] <= Ty + 31) && (ayr[r] + TILE_ - 1 >= Ty);
        mr[r] = __ballot(ovr[r] ? 1 : 0);
        if (lane == 0) s_wcnt[r * 4 + w] = __popcll(mr[r]);
    }
    __syncthreads();
    {
        int tot = 0, pre[2];
        for (int i = 0; i < 8; ++i) {
            const int rr = i >> 2, ww = i & 3;
            if (rr * 4 + ww == 0 * 4 + w && rr == 0) {}
            if (i == 0 * 4 + w + 0) {}
            tot += 0;
        }
        // straightforward prefix: position of (r,w) = sum of s_wcnt[0 .. r*4+w-1]
        int total = 0;
        for (int i = 0; i < 8; ++i) total += s_wcnt[i];
        #pragma unroll
        for (int r = 0; r < 2; ++r) {
            int base = 0;
            for (int i = 0; i < r * 4 + w; ++i) base += s_wcnt[i];
            if (ovr[r]) {
                const int pos = base + __popcll(mr[r] & ((1ull << lane) - 1ull));
                s_c[pos]  = (unsigned short)(r * 256 + tid);
                s_ax[pos] = (short)axr[r];
                s_ay[pos] = (short)ayr[r];
            }
        }
        if (tid == 0) s_cnt = total;
    }
    __syncthreads();

    // accumulate 4 px per thread (row-major float4), fixed ascending-ish chunk order
    const int cnt = s_cnt;
    const int row = tid >> 3;                  // 0..31
    const int c0  = (tid & 7) * 4;             // 0,4,..,28
    const int gx  = Tx + row;
    float4_ acc = {0.f, 0.f, 0.f, 0.f};
    for (int p = 0; p < cnt; ++p) {
        const int rr = gx - (int)s_ax[p];
        if ((unsigned)rr < (unsigned)TILE_) {
            const float* wrow = wst + (size_t)s_c[p] * WSTILE + rr * TILE_;
            const int cc = Ty + c0 - (int)s_ay[p];
            #pragma unroll
            for (int i = 0; i < 4; ++i) {
                const int ci = cc + i;
                if ((unsigned)ci < (unsigned)TILE_) acc[i] += wrow[ci];
            }
        }
    }
    *(float4_*)&out[(size_t)gx * RES_ + Ty + c0] = acc;   // cnt==0 -> zeros (no memset needed)
}

extern "C" void kernel_launch(void* const* d_in, const int* in_sizes, int n_in,
                              void* d_out, int out_size, void* d_ws, size_t ws_size,
                              hipStream_t stream) {
    const float* cp = (const float*)d_in[0];
    float* out = (float*)d_out;
    float* wst = (float*)d_ws;                                   // 512 * 2304 floats = 4.72 MB
    int*   wsa = (int*)((char*)d_ws + (size_t)NCH * WSTILE * 4); // 512 int2 anchors

    hipLaunchKernelGGL(bezier_chunks, dim3(NCH), dim3(NTHR1), 0, stream, cp, wst, wsa);
    hipLaunchKernelGGL(bezier_gather, dim3(4096), dim3(NTHR2), 0, stream, wst, wsa, out);
}

// Round 7
// 24.538 us; speedup vs baseline: 2.5001x; 1.5049x over previous
//
#include <hip/hip_runtime.h>
#include <hip/hip_bf16.h>

#define RES_    2048
#define CSTEPS  128     // steps per workgroup
#define TILE_   48      // span <= 8px movement + 32 window = 40 <= 48 (3x3 MFMA tiles)
#define KPAD    136     // 128 + 8 halfs pad: row stride 272B, 16B-aligned
#define NTHR    576     // 9 waves: one 16x16 output tile each

typedef _Float16 half8 __attribute__((ext_vector_type(8)));
typedef float   float4_ __attribute__((ext_vector_type(4)));

__global__ __launch_bounds__(1024) void zero_out(float4_* __restrict__ out) {
    out[(size_t)blockIdx.x * 1024 + threadIdx.x] = float4_{0.f, 0.f, 0.f, 0.f};
}

// Calibration node: measures per-node graph-replay overhead h (body never executes a store).
__global__ void empty_k(float* __restrict__ out) {
    if (threadIdx.x > 1024) out[0] = 1.0f;   // never true; prevents total elision
}

__global__ __launch_bounds__(NTHR) void bezier_scatter(const float* __restrict__ cp,
                                                       float* __restrict__ out) {
    __shared__ _Float16 sExT[TILE_][KPAD];   // [col_offset][step], masked exp_x
    __shared__ _Float16 sEyT[TILE_][KPAD];   // [col_offset][step], masked exp_y
    __shared__ float s_cx[CSTEPS], s_cy[CSTEPS];
    __shared__ int   s_bx[CSTEPS], s_by[CSTEPS];
    __shared__ int   s_Ax, s_Ay;

    const int tid = threadIdx.x;

    // ---- Phase A: per-step curve position & block corner (exact ref float32 math) ----
    if (tid < CSTEPS) {
        const int gs = blockIdx.x * CSTEPS + tid;
        const float tl = (float)((double)gs / 65535.0);      // linspace(0,1,STEPS)
        const float to = (float)gs * (1.0f / 65536.0f);      // arange(STEPS)/STEPS (exact)
        const float p0x = cp[0], p0y = cp[1], p1x = cp[2], p1y = cp[3], p2x = cp[4], p2y = cp[5];
        const float ax = __fadd_rn(p0x, __fmul_rn(__fsub_rn(p1x, p0x), tl));
        const float ay = __fadd_rn(p0y, __fmul_rn(__fsub_rn(p1y, p0y), tl));
        const float bxf = __fadd_rn(p1x, __fmul_rn(__fsub_rn(p2x, p1x), tl));
        const float byf = __fadd_rn(p1y, __fmul_rn(__fsub_rn(p2y, p1y), tl));
        const float cx = __fadd_rn(ax, __fmul_rn(to, __fsub_rn(bxf, ax)));
        const float cy = __fadd_rn(ay, __fmul_rn(to, __fsub_rn(byf, ay)));
        const int bxi = min(max((int)floorf(__fmul_rn(2048.0f, cx)) - 16, 0), RES_ - 32);
        const int byi = min(max((int)floorf(__fmul_rn(2048.0f, cy)) - 16, 0), RES_ - 32);
        s_cx[tid] = cx; s_cy[tid] = cy; s_bx[tid] = bxi; s_by[tid] = byi;
        if (tid == 0) {
            // |bx_s - bx_0| <= 8 over 128 steps -> windows subset of [bx0-8, bx0+40) (48 wide)
            s_Ax = min(max(bxi - 8, 0), RES_ - TILE_);
            s_Ay = min(max(byi - 8, 0), RES_ - TILE_);
        }
    }
    __syncthreads();
    const int Ax = s_Ax, Ay = s_Ay;

    // ---- Phase B: fill masked transposed f16 exp tables ----
    for (int it = tid; it < 2 * TILE_ * (CSTEPS / 8); it += NTHR) {
        const int half_ = TILE_ * (CSTEPS / 8);       // 768
        const int table = (it >= half_);
        const int rem   = it - table * half_;
        const int o     = rem >> 4;                   // tile col offset 0..47
        const int s0    = (rem & 15) * 8;             // step group start
        const float* cc = table ? s_cy : s_cx;
        const int*   bb = table ? s_by : s_bx;
        const int  base = table ? Ay : Ax;
        const float ci  = (float)(base + o) * (1.0f / 2048.0f);   // exact (pow2 div)
        half8 v;
        #pragma unroll
        for (int j = 0; j < 8; ++j) {
            const int s = s0 + j;
            const float d = __fsub_rn(cc[s], ci);
            const float e = __expf(-__fmul_rn(__fmul_rn(d, d), 5000.0f));
            const unsigned orel = (unsigned)(base + o - bb[s]);
            v[j] = (orel < 32u) ? (_Float16)e : (_Float16)0.0f;
        }
        *(half8*)(table ? &sEyT[o][s0] : &sExT[o][s0]) = v;
    }
    __syncthreads();

    // ---- Phase C: 48x48 tile = Ex^T (48x128) * Ey (128x48); 9 waves, 1 tile each ----
    const int lane = tid & 63;
    const int wid  = tid >> 6;          // 0..8
    const int mt   = wid / 3, nt = wid - mt * 3;
    const int arow = mt * 16 + (lane & 15);
    const int bcol = nt * 16 + (lane & 15);
    const int kgrp = (lane >> 4) * 8;
    float4_ acc = {0.f, 0.f, 0.f, 0.f};
    #pragma unroll
    for (int kb = 0; kb < CSTEPS / 32; ++kb) {
        const half8 aF = *(const half8*)&sExT[arow][kb * 32 + kgrp];
        const half8 bF = *(const half8*)&sEyT[bcol][kb * 32 + kgrp];
        acc = __builtin_amdgcn_mfma_f32_16x16x32_f16(aF, bF, acc, 0, 0, 0);
    }

    // ---- Flush: C/D layout col = lane&15, row = (lane>>4)*4 + reg (confirmed R1) ----
    const int coll = lane & 15;
    const int rowb = (lane >> 4) * 4;
    #pragma unroll
    for (int r = 0; r < 4; ++r) {
        const float v = acc[r];
        if (v != 0.0f) {   // nonzero only inside valid clamped windows
            const int gx = Ax + mt * 16 + rowb + r;
            const int gy = Ay + nt * 16 + coll;
            atomicAdd(&out[gx * RES_ + gy], v * (1.0f / 65536.0f));  // /STEPS exact (pow2)
        }
    }
}

extern "C" void kernel_launch(void* const* d_in, const int* in_sizes, int n_in,
                              void* d_out, int out_size, void* d_ws, size_t ws_size,
                              hipStream_t stream) {
    const float* cp = (const float*)d_in[0];
    float* out = (float*)d_out;
    // R4 structure, unchanged:
    hipLaunchKernelGGL(zero_out, dim3(1024), dim3(1024), 0, stream, (float4_*)out);
    hipLaunchKernelGGL(bezier_scatter, dim3(65536 / CSTEPS), dim3(NTHR), 0, stream, cp, out);
    // Calibration: two empty nodes -> dur = R4_dur + 2h
    hipLaunchKernelGGL(empty_k, dim3(1), dim3(64), 0, stream, out);
    hipLaunchKernelGGL(empty_k, dim3(1), dim3(64), 0, stream, out);
}